// Round 4
// baseline (1354.374 us; speedup 1.0000x reference)
//
#include <hip/hip_runtime.h>
#include <hip/hip_cooperative_groups.h>
#include <math.h>

namespace cg = cooperative_groups;

#define N_NODE    1000000
#define N_BOND    100000
#define K_TWIST   40
#define MAX_ORDER 8
#define N_DOMAIN  10000
#define N_PER_DOM 100           // N_NODE / N_DOMAIN
#define N_GROUP   12500         // N_BOND / MAX_ORDER
#define N_TWIST   500000        // N_GROUP * K_TWIST  (nodes >= N_TWIST never twisted)
#define SIGMA_MAXF 3.14159265358979323846f

#define MEGA_BLOCKS  1024
#define MEGA_THREADS 256
#define GRID_THREADS (MEGA_BLOCKS * MEGA_THREADS)   // 262144
#define GRID_WAVES   (GRID_THREADS / 64)            // 4096

// ws budget: EXACTLY 480,000 bytes (rt table) — proven safe (R1/R3). Larger
// scratch (M ping-pong 2x600KB + sums 600KB) lives in the HIGH half of d_out
// (floats [1.5M, 3M)), which is only written in the final phase after all
// scratch reads are done.

// ---------------------------------------------------------------------------
// 3x3 SVD-based Kabsch from 15 sums (double Jacobi on H^T H) — numerics
// identical to the R1/R3-verified version. s has stride-1 15 floats.
// Writes rt[0..11] = [R row-major | t].
// ---------------------------------------------------------------------------
__device__ inline void cross3d(const double a[3], const double b[3], double r[3])
{
    r[0] = a[1]*b[2] - a[2]*b[1];
    r[1] = a[2]*b[0] - a[0]*b[2];
    r[2] = a[0]*b[1] - a[1]*b[0];
}

__device__ void kabsch_from_sums(const float* s, float* __restrict__ rt)
{
    const double inv_n = 1.0 / (double)N_PER_DOM;
    double sP[3] = { s[0], s[1], s[2] };
    double sQ[3] = { s[3], s[4], s[5] };
    double H[3][3];
    #pragma unroll
    for (int i = 0; i < 3; i++)
        #pragma unroll
        for (int j = 0; j < 3; j++)
            H[i][j] = (double)s[6 + 3*i + j] - sP[i]*sQ[j]*inv_n;
    double A[3][3];
    #pragma unroll
    for (int i = 0; i < 3; i++)
        #pragma unroll
        for (int j = 0; j < 3; j++)
            A[i][j] = H[0][i]*H[0][j] + H[1][i]*H[1][j] + H[2][i]*H[2][j];
    double V[3][3] = {{1,0,0},{0,1,0},{0,0,1}};
    for (int sweep = 0; sweep < 30; sweep++) {
        double off = A[0][1]*A[0][1] + A[0][2]*A[0][2] + A[1][2]*A[1][2];
        double n2  = A[0][0]*A[0][0] + A[1][1]*A[1][1] + A[2][2]*A[2][2];
        if (off <= 1e-28 * n2) break;
        for (int pp = 0; pp < 3; pp++) {
            int p = (pp == 2) ? 1 : 0;
            int q = (pp == 0) ? 1 : 2;
            double apq = A[p][q];
            if (apq == 0.0) continue;
            double tau = (A[q][q] - A[p][p]) / (2.0 * apq);
            double tj  = (tau >= 0.0 ? 1.0 : -1.0) / (fabs(tau) + sqrt(1.0 + tau*tau));
            double cj  = 1.0 / sqrt(1.0 + tj*tj);
            double sj  = tj * cj;
            int r = 3 - p - q;
            double app = A[p][p], aqq = A[q][q];
            A[p][p] = app - tj*apq;
            A[q][q] = aqq + tj*apq;
            A[p][q] = 0.0; A[q][p] = 0.0;
            double arp = A[r][p], arq = A[r][q];
            A[r][p] = cj*arp - sj*arq; A[p][r] = A[r][p];
            A[r][q] = sj*arp + cj*arq; A[q][r] = A[r][q];
            #pragma unroll
            for (int k = 0; k < 3; k++) {
                double vp = V[k][p], vq = V[k][q];
                V[k][p] = cj*vp - sj*vq;
                V[k][q] = sj*vp + cj*vq;
            }
        }
    }
    double wv[3] = { A[0][0], A[1][1], A[2][2] };
    int i0 = 0, i1 = 1, i2 = 2;
    if (wv[i0] < wv[i1]) { int t = i0; i0 = i1; i1 = t; }
    if (wv[i0] < wv[i2]) { int t = i0; i0 = i2; i2 = t; }
    if (wv[i1] < wv[i2]) { int t = i1; i1 = i2; i2 = t; }
    double v0[3] = { V[0][i0], V[1][i0], V[2][i0] };
    double v1[3] = { V[0][i1], V[1][i1], V[2][i1] };
    double v2[3] = { V[0][i2], V[1][i2], V[2][i2] };
    double s0 = sqrt(fmax(wv[i0], 0.0));
    double Rg[3][3];
    if (s0 < 1e-200) {
        Rg[0][0]=1; Rg[0][1]=0; Rg[0][2]=0;
        Rg[1][0]=0; Rg[1][1]=1; Rg[1][2]=0;
        Rg[2][0]=0; Rg[2][1]=0; Rg[2][2]=1;
    } else {
        double u0[3], u1[3], u2[3];
        #pragma unroll
        for (int i = 0; i < 3; i++)
            u0[i] = H[i][0]*v0[0] + H[i][1]*v0[1] + H[i][2]*v0[2];
        double n0 = sqrt(u0[0]*u0[0] + u0[1]*u0[1] + u0[2]*u0[2]);
        if (n0 > 0.0) { u0[0]/=n0; u0[1]/=n0; u0[2]/=n0; }
        else { u0[0]=1; u0[1]=0; u0[2]=0; }
        #pragma unroll
        for (int i = 0; i < 3; i++)
            u1[i] = H[i][0]*v1[0] + H[i][1]*v1[1] + H[i][2]*v1[2];
        double dp = u0[0]*u1[0] + u0[1]*u1[1] + u0[2]*u1[2];
        u1[0] -= dp*u0[0]; u1[1] -= dp*u0[1]; u1[2] -= dp*u0[2];
        double n1 = sqrt(u1[0]*u1[0] + u1[1]*u1[1] + u1[2]*u1[2]);
        if (n1 > 1e-12 * n0) { u1[0]/=n1; u1[1]/=n1; u1[2]/=n1; }
        else {
            double tv[3] = { (fabs(u0[0]) < 0.9) ? 1.0 : 0.0,
                             (fabs(u0[0]) < 0.9) ? 0.0 : 1.0, 0.0 };
            cross3d(u0, tv, u1);
            double nn = sqrt(u1[0]*u1[0] + u1[1]*u1[1] + u1[2]*u1[2]);
            u1[0]/=nn; u1[1]/=nn; u1[2]/=nn;
        }
        cross3d(u0, u1, u2);                    // det(U) = +1
        double c12[3]; cross3d(v1, v2, c12);
        double detV = v0[0]*c12[0] + v0[1]*c12[1] + v0[2]*c12[2];
        double dsg = (detV >= 0.0) ? 1.0 : -1.0;
        #pragma unroll
        for (int r = 0; r < 3; r++)
            #pragma unroll
            for (int c = 0; c < 3; c++)
                Rg[r][c] = v0[r]*u0[c] + v1[r]*u1[c] + dsg*v2[r]*u2[c];
    }
    double cP[3] = { sP[0]*inv_n, sP[1]*inv_n, sP[2]*inv_n };
    double cQ[3] = { sQ[0]*inv_n, sQ[1]*inv_n, sQ[2]*inv_n };
    #pragma unroll
    for (int i = 0; i < 3; i++) {
        rt[3*i+0] = (float)Rg[i][0];
        rt[3*i+1] = (float)Rg[i][1];
        rt[3*i+2] = (float)Rg[i][2];
        rt[9+i] = (float)(cQ[i] - (Rg[i][0]*cP[0] + Rg[i][1]*cP[1] + Rg[i][2]*cP[2]));
    }
}

// ---------------------------------------------------------------------------
// Cooperative mega-kernel: the whole pipeline in one dispatch.
// Key idea: never materialize intermediate positions. Track per-group
// cumulative affine M_g (x -> A x + t). Order o only needs positions of the
// two bond endpoints, reconstructed as M[their group] * pos.
// ---------------------------------------------------------------------------
__global__ void __launch_bounds__(MEGA_THREADS, 4) mega_k(
    const float* __restrict__ pos, const float* __restrict__ info_level,
    const int* __restrict__ anno, const float* __restrict__ eps,
    const float* __restrict__ uni, const int* __restrict__ from_prior_p,
    float* out, float* __restrict__ rt)
{
    cg::grid_group grid = cg::this_grid();
    const int tid = blockIdx.x * MEGA_THREADS + threadIdx.x;

    // scratch in the high half of d_out (floats [1.5M, 3M))
    float* M0   = out + (size_t)3 * N_TWIST;          // 150,000 floats
    float* M1   = M0 + 12 * N_GROUP;                  // 150,000 floats
    float* sums = M1 + 12 * N_GROUP;                  // 150,000 floats
    const int from_prior = from_prior_p[0];

    // ---- Phase T: compose per-group affines over 8 orders -----------------
    for (int o = 0; o < MAX_ORDER; o++) {
        const float* Mp = (o & 1) ? M0 : M1;   // prev (unused at o=0)
        float*       Mc = (o & 1) ? M1 : M0;   // cur  (o=7 -> M1)
        if (tid < N_GROUP) {
            int g = tid;
            int b = g * MAX_ORDER + o;
            float* mg = Mc + 12 * g;
            if (anno[3*b] != o) {                       // safety fallback
                if (o == 0) {
                    mg[0]=1.f; mg[1]=0.f; mg[2]=0.f;
                    mg[3]=0.f; mg[4]=1.f; mg[5]=0.f;
                    mg[6]=0.f; mg[7]=0.f; mg[8]=1.f;
                    mg[9]=0.f; mg[10]=0.f; mg[11]=0.f;
                } else {
                    const float* mp = Mp + 12 * g;
                    #pragma unroll
                    for (int k = 0; k < 12; k++) mg[k] = mp[k];
                }
            } else {
                int u = anno[3*b + 1];
                int v = anno[3*b + 2];
                float pu0 = pos[3*u+0], pu1 = pos[3*u+1], pu2 = pos[3*u+2];
                float pv0 = pos[3*v+0], pv1 = pos[3*v+1], pv2 = pos[3*v+2];
                if (o > 0) {
                    if (u < N_TWIST) {
                        const float* m = Mp + 12 * (u / K_TWIST);
                        float a = m[0]*pu0 + m[1]*pu1 + m[2]*pu2 + m[9];
                        float c = m[3]*pu0 + m[4]*pu1 + m[5]*pu2 + m[10];
                        float e = m[6]*pu0 + m[7]*pu1 + m[8]*pu2 + m[11];
                        pu0 = a; pu1 = c; pu2 = e;
                    }
                    if (v < N_TWIST) {
                        const float* m = Mp + 12 * (v / K_TWIST);
                        float a = m[0]*pv0 + m[1]*pv1 + m[2]*pv2 + m[9];
                        float c = m[3]*pv0 + m[4]*pv1 + m[5]*pv2 + m[10];
                        float e = m[6]*pv0 + m[7]*pv1 + m[8]*pv2 + m[11];
                        pv0 = a; pv1 = c; pv2 = e;
                    }
                }
                float info = info_level[b];
                float ang  = eps[b] * (1.0f - info) * SIGMA_MAXF;
                if (from_prior != 0 && info == 0.0f) ang = uni[b];
                float ax = pv0-pu0, ay = pv1-pu1, az = pv2-pu2;
                float inv = 1.0f / (sqrtf(ax*ax + ay*ay + az*az) + 1e-12f);
                ax *= inv; ay *= inv; az *= inv;
                float c = cosf(ang), s = sinf(ang), t = 1.0f - c;
                float R00 = c + t*ax*ax,     R01 = -s*az + t*ax*ay, R02 =  s*ay + t*ax*az;
                float R10 =  s*az + t*ay*ax, R11 = c + t*ay*ay,     R12 = -s*ax + t*ay*az;
                float R20 = -s*ay + t*az*ax, R21 =  s*ax + t*az*ay, R22 = c + t*az*az;
                if (o == 0) {
                    // M = (R, p - R p), p = pv
                    mg[0]=R00; mg[1]=R01; mg[2]=R02;
                    mg[3]=R10; mg[4]=R11; mg[5]=R12;
                    mg[6]=R20; mg[7]=R21; mg[8]=R22;
                    mg[9]  = pv0 - (R00*pv0 + R01*pv1 + R02*pv2);
                    mg[10] = pv1 - (R10*pv0 + R11*pv1 + R12*pv2);
                    mg[11] = pv2 - (R20*pv0 + R21*pv1 + R22*pv2);
                } else {
                    const float* mp = Mp + 12 * g;
                    // A_cur = R * A_prev
                    mg[0] = R00*mp[0] + R01*mp[3] + R02*mp[6];
                    mg[1] = R00*mp[1] + R01*mp[4] + R02*mp[7];
                    mg[2] = R00*mp[2] + R01*mp[5] + R02*mp[8];
                    mg[3] = R10*mp[0] + R11*mp[3] + R12*mp[6];
                    mg[4] = R10*mp[1] + R11*mp[4] + R12*mp[7];
                    mg[5] = R10*mp[2] + R11*mp[5] + R12*mp[8];
                    mg[6] = R20*mp[0] + R21*mp[3] + R22*mp[6];
                    mg[7] = R20*mp[1] + R21*mp[4] + R22*mp[7];
                    mg[8] = R20*mp[2] + R21*mp[5] + R22*mp[8];
                    // t_cur = R*(t_prev - p) + p
                    float d0 = mp[9]-pv0, d1 = mp[10]-pv1, d2 = mp[11]-pv2;
                    mg[9]  = R00*d0 + R01*d1 + R02*d2 + pv0;
                    mg[10] = R10*d0 + R11*d1 + R12*d2 + pv1;
                    mg[11] = R20*d0 + R21*d1 + R22*d2 + pv2;
                }
            }
        }
        grid.sync();
    }
    const float* Mf = M1;   // final cumulative affine (after o=7)

    // ---- Phase R: wave-per-domain reduce, P = Mf * pos on the fly ---------
    {
        int wid  = tid >> 6;
        int lane = tid & 63;
        for (int d = wid; d < N_DOMAIN; d += GRID_WAVES) {
            float a[15];
            #pragma unroll
            for (int k = 0; k < 15; k++) a[k] = 0.f;
            for (int i = lane; i < N_PER_DOM; i += 64) {
                int n = d * N_PER_DOM + i;
                float q0 = pos[3*n+0], q1 = pos[3*n+1], q2 = pos[3*n+2];
                float p0 = q0, p1 = q1, p2 = q2;
                if (n < N_TWIST) {
                    const float* m = Mf + 12 * (n / K_TWIST);
                    p0 = m[0]*q0 + m[1]*q1 + m[2]*q2 + m[9];
                    p1 = m[3]*q0 + m[4]*q1 + m[5]*q2 + m[10];
                    p2 = m[6]*q0 + m[7]*q1 + m[8]*q2 + m[11];
                }
                a[0]+=p0;    a[1]+=p1;    a[2]+=p2;
                a[3]+=q0;    a[4]+=q1;    a[5]+=q2;
                a[6]+=p0*q0; a[7]+=p0*q1; a[8]+=p0*q2;
                a[9]+=p1*q0; a[10]+=p1*q1;a[11]+=p1*q2;
                a[12]+=p2*q0;a[13]+=p2*q1;a[14]+=p2*q2;
            }
            #pragma unroll
            for (int off = 32; off > 0; off >>= 1)
                #pragma unroll
                for (int k = 0; k < 15; k++) a[k] += __shfl_down(a[k], off);
            if (lane == 0) {
                float* sd = sums + (size_t)d * 15;
                #pragma unroll
                for (int k = 0; k < 15; k++) sd[k] = a[k];
            }
        }
    }
    grid.sync();

    // ---- Phase S: thread-per-domain SVD (all 64 lanes useful) -------------
    if (tid < N_DOMAIN)
        kabsch_from_sums(sums + (size_t)tid * 15, rt + (size_t)tid * 12);
    grid.sync();

    // ---- Phase A1: corrected low nodes -> out[0 .. 1.5M) ------------------
    for (int n = tid; n < N_TWIST; n += GRID_THREADS) {
        const float* m = Mf + 12 * (n / K_TWIST);
        const float* w = rt + 12 * (n / N_PER_DOM);
        float q0 = pos[3*n+0], q1 = pos[3*n+1], q2 = pos[3*n+2];
        float p0 = m[0]*q0 + m[1]*q1 + m[2]*q2 + m[9];
        float p1 = m[3]*q0 + m[4]*q1 + m[5]*q2 + m[10];
        float p2 = m[6]*q0 + m[7]*q1 + m[8]*q2 + m[11];
        out[3*n+0] = w[0]*p0 + w[1]*p1 + w[2]*p2 + w[9];
        out[3*n+1] = w[3]*p0 + w[4]*p1 + w[5]*p2 + w[10];
        out[3*n+2] = w[6]*p0 + w[7]*p1 + w[8]*p2 + w[11];
    }
    grid.sync();   // Mf/sums fully consumed; A2 may now overwrite scratch

    // ---- Phase A2: corrected high nodes -> out[1.5M .. 3M) ----------------
    for (int n = N_TWIST + tid; n < N_NODE; n += GRID_THREADS) {
        const float* w = rt + 12 * (n / N_PER_DOM);
        float q0 = pos[3*n+0], q1 = pos[3*n+1], q2 = pos[3*n+2];
        out[3*n+0] = w[0]*q0 + w[1]*q1 + w[2]*q2 + w[9];
        out[3*n+1] = w[3]*q0 + w[4]*q1 + w[5]*q2 + w[10];
        out[3*n+2] = w[6]*q0 + w[7]*q1 + w[8]*q2 + w[11];
    }
}

// ===========================================================================
// Fallback path: R3-proven pipeline (8x tor_fused + kab_rsvd + kab_apply),
// used only if the cooperative launch is rejected.
// ===========================================================================
#define GPB       8
#define TOR_BLOCK (GPB * K_TWIST)

__device__ inline void gather_node(const float* __restrict__ lowbuf,
                                   const float* __restrict__ pos,
                                   int n, float* x, float* y, float* z)
{
    const float* p = (n < N_TWIST) ? (lowbuf + 3*(size_t)n) : (pos + 3*(size_t)n);
    *x = p[0]; *y = p[1]; *z = p[2];
}

__global__ __launch_bounds__(TOR_BLOCK) void tor_fused_k(
    const float* __restrict__ srcLow, const float* __restrict__ pos,
    float* __restrict__ dstLow,
    const int* __restrict__ anno, const float* __restrict__ info_level,
    const float* __restrict__ eps, const float* __restrict__ uni,
    const int* __restrict__ from_prior, int o)
{
    __shared__ float R[GPB][12];
    int tid = threadIdx.x;
    int g0  = blockIdx.x * GPB;
    int gi  = tid / K_TWIST;
    int g   = g0 + gi;
    int n   = g * K_TWIST + (tid - gi * K_TWIST);
    bool act = (g < N_GROUP);
    float x = 0.f, y = 0.f, z = 0.f;
    if (act) { x = srcLow[3*n+0]; y = srcLow[3*n+1]; z = srcLow[3*n+2]; }
    if (tid < GPB && (g0 + tid) < N_GROUP) {
        int b = ((g0 + tid) * MAX_ORDER) + o;
        float* w = R[tid];
        if (anno[3*b + 0] != o) {
            w[0]=1.f; w[1]=0.f; w[2]=0.f;
            w[3]=0.f; w[4]=1.f; w[5]=0.f;
            w[6]=0.f; w[7]=0.f; w[8]=1.f;
            w[9]=0.f; w[10]=0.f; w[11]=0.f;
        } else {
            int u = anno[3*b + 1];
            int v = anno[3*b + 2];
            float info = info_level[b];
            float ang  = eps[b] * (1.0f - info) * SIGMA_MAXF;
            if (from_prior[0] != 0 && info == 0.0f) ang = uni[b];
            float ux, uy, uz, px, py, pz;
            gather_node(srcLow, pos, u, &ux, &uy, &uz);
            gather_node(srcLow, pos, v, &px, &py, &pz);
            float ax = px-ux, ay = py-uy, az = pz-uz;
            float inv = 1.0f / (sqrtf(ax*ax + ay*ay + az*az) + 1e-12f);
            ax *= inv; ay *= inv; az *= inv;
            float c = cosf(ang), s = sinf(ang), t = 1.0f - c;
            w[0] = c + t*ax*ax;      w[1] = -s*az + t*ax*ay;  w[2] =  s*ay + t*ax*az;
            w[3] =  s*az + t*ay*ax;  w[4] = c + t*ay*ay;      w[5] = -s*ax + t*ay*az;
            w[6] = -s*ay + t*az*ax;  w[7] =  s*ax + t*az*ay;  w[8] = c + t*az*az;
            w[9] = px; w[10] = py; w[11] = pz;
        }
    }
    __syncthreads();
    if (act) {
        const float* w = R[gi];
        float dx = x - w[9], dy = y - w[10], dz = z - w[11];
        dstLow[3*n+0] = w[0]*dx + w[1]*dy + w[2]*dz + w[9];
        dstLow[3*n+1] = w[3]*dx + w[4]*dy + w[5]*dz + w[10];
        dstLow[3*n+2] = w[6]*dx + w[7]*dy + w[8]*dz + w[11];
    }
}

__global__ __launch_bounds__(256) void kab_rsvd_k(const float* __restrict__ low,
                                                  const float* __restrict__ pos,
                                                  float* __restrict__ rt)
{
    int wave = threadIdx.x >> 6;
    int lane = threadIdx.x & 63;
    int d = blockIdx.x * 4 + wave;
    const float* Psrc = (d < 5000) ? low : pos;
    float a[15];
    #pragma unroll
    for (int k = 0; k < 15; k++) a[k] = 0.f;
    for (int i = lane; i < N_PER_DOM; i += 64) {
        int n = d * N_PER_DOM + i;
        float p0 = Psrc[3*n+0], p1 = Psrc[3*n+1], p2 = Psrc[3*n+2];
        float q0 = pos[3*n+0],  q1 = pos[3*n+1],  q2 = pos[3*n+2];
        a[0]+=p0;    a[1]+=p1;    a[2]+=p2;
        a[3]+=q0;    a[4]+=q1;    a[5]+=q2;
        a[6]+=p0*q0; a[7]+=p0*q1; a[8]+=p0*q2;
        a[9]+=p1*q0; a[10]+=p1*q1;a[11]+=p1*q2;
        a[12]+=p2*q0;a[13]+=p2*q1;a[14]+=p2*q2;
    }
    #pragma unroll
    for (int off = 32; off > 0; off >>= 1)
        #pragma unroll
        for (int k = 0; k < 15; k++) a[k] += __shfl_down(a[k], off);
    if (lane == 0)
        kabsch_from_sums(a, rt + (size_t)d * 12);
}

__global__ void kab_apply_k(float* out, const float* __restrict__ pos,
                            const float* __restrict__ rt)
{
    int i = blockIdx.x * blockDim.x + threadIdx.x;
    if (i >= N_NODE) return;
    int d = i / N_PER_DOM;
    const float* w = rt + (size_t)d * 12;
    float x, y, z;
    if (i < N_TWIST) { x = out[3*i+0]; y = out[3*i+1]; z = out[3*i+2]; }
    else             { x = pos[3*i+0]; y = pos[3*i+1]; z = pos[3*i+2]; }
    out[3*i+0] = w[0]*x + w[1]*y + w[2]*z + w[9];
    out[3*i+1] = w[3]*x + w[4]*y + w[5]*z + w[10];
    out[3*i+2] = w[6]*x + w[7]*y + w[8]*z + w[11];
}

// ---------------------------------------------------------------------------
extern "C" void kernel_launch(void* const* d_in, const int* in_sizes, int n_in,
                              void* d_out, int out_size, void* d_ws, size_t ws_size,
                              hipStream_t stream)
{
    const float* pos        = (const float*)d_in[0];
    const float* info_level = (const float*)d_in[1];
    const int*   anno       = (const int*)  d_in[2];
    const float* eps        = (const float*)d_in[6];
    const float* uni        = (const float*)d_in[7];
    const int*   from_prior = (const int*)  d_in[8];
    float* out = (float*)d_out;
    float* rt  = (float*)d_ws;                      // 10000*12 floats = 480,000 B

    void* args[] = { (void*)&pos, (void*)&info_level, (void*)&anno, (void*)&eps,
                     (void*)&uni, (void*)&from_prior, (void*)&out, (void*)&rt };
    hipError_t err = hipLaunchCooperativeKernel(
        (const void*)mega_k, dim3(MEGA_BLOCKS), dim3(MEGA_THREADS), args, 0, stream);

    if (err != hipSuccess) {
        (void)hipGetLastError();    // clear sticky error; run R3-proven fallback
        float* L0 = out;
        float* L1 = out + (size_t)3 * N_TWIST;
        const int tor_blocks = (N_GROUP + GPB - 1) / GPB;
        for (int o = 0; o < MAX_ORDER; o++) {
            const float* src = (o == 0) ? pos : ((o & 1) ? (const float*)L1 : (const float*)L0);
            float*       dst = (o & 1) ? L0 : L1;
            tor_fused_k<<<tor_blocks, TOR_BLOCK, 0, stream>>>(
                src, pos, dst, anno, info_level, eps, uni, from_prior, o);
        }
        kab_rsvd_k<<<N_DOMAIN / 4, 256, 0, stream>>>(L0, pos, rt);
        kab_apply_k<<<(N_NODE + 255) / 256, 256, 0, stream>>>(out, pos, rt);
    }
}

// Round 5
// 165.317 us; speedup vs baseline: 8.1926x; 8.1926x over previous
//
#include <hip/hip_runtime.h>
#include <math.h>

#define N_NODE    1000000
#define N_BOND    100000
#define K_TWIST   40
#define MAX_ORDER 8
#define N_DOMAIN  10000
#define N_PER_DOM 100           // N_NODE / N_DOMAIN
#define N_GROUP   12500         // N_BOND / MAX_ORDER
#define N_TWIST   500000        // N_GROUP * K_TWIST  (nodes >= N_TWIST never twisted)
#define SIGMA_MAXF 3.14159265358979323846f

// Scratch layout (R4-proven):
//   ws: rt table, 10000*12 floats = 480,000 B (proven-safe footprint)
//   out-high (floats [1.5M,3M)): M0 | M1 | sums  (150k floats each)
//   - M/sums are consumed before apply_high overwrites that region.
// R4 lesson: grid.sync() costs ~110 us each on MI355X (8 non-coherent XCDs);
// stream-ordered dispatch boundaries (~2-4 us) are the cheap barrier here.

// ---------------------------------------------------------------------------
// compose_k: one thread per group. Order o's rotation is composed onto the
// per-group cumulative affine M_g (x -> A x + t). Endpoint positions are
// reconstructed as M[group(n)] * pos[n] (math verified in R4, absmax 0.25).
// ---------------------------------------------------------------------------
__global__ __launch_bounds__(256) void compose_k(
    const float* __restrict__ pos, const float* __restrict__ info_level,
    const int* __restrict__ anno, const float* __restrict__ eps,
    const float* __restrict__ uni, const int* __restrict__ from_prior_p,
    const float* __restrict__ Mp, float* __restrict__ Mc, int o)
{
    int g = blockIdx.x * 256 + threadIdx.x;
    if (g >= N_GROUP) return;
    int b = g * MAX_ORDER + o;
    float* mg = Mc + 12 * g;
    if (anno[3*b] != o) {                       // safety fallback
        if (o == 0) {
            mg[0]=1.f; mg[1]=0.f; mg[2]=0.f;
            mg[3]=0.f; mg[4]=1.f; mg[5]=0.f;
            mg[6]=0.f; mg[7]=0.f; mg[8]=1.f;
            mg[9]=0.f; mg[10]=0.f; mg[11]=0.f;
        } else {
            const float* mp = Mp + 12 * g;
            #pragma unroll
            for (int k = 0; k < 12; k++) mg[k] = mp[k];
        }
        return;
    }
    int u = anno[3*b + 1];
    int v = anno[3*b + 2];
    float pu0 = pos[3*u+0], pu1 = pos[3*u+1], pu2 = pos[3*u+2];
    float pv0 = pos[3*v+0], pv1 = pos[3*v+1], pv2 = pos[3*v+2];
    if (o > 0) {
        if (u < N_TWIST) {
            const float* m = Mp + 12 * (u / K_TWIST);
            float a = m[0]*pu0 + m[1]*pu1 + m[2]*pu2 + m[9];
            float c = m[3]*pu0 + m[4]*pu1 + m[5]*pu2 + m[10];
            float e = m[6]*pu0 + m[7]*pu1 + m[8]*pu2 + m[11];
            pu0 = a; pu1 = c; pu2 = e;
        }
        if (v < N_TWIST) {
            const float* m = Mp + 12 * (v / K_TWIST);
            float a = m[0]*pv0 + m[1]*pv1 + m[2]*pv2 + m[9];
            float c = m[3]*pv0 + m[4]*pv1 + m[5]*pv2 + m[10];
            float e = m[6]*pv0 + m[7]*pv1 + m[8]*pv2 + m[11];
            pv0 = a; pv1 = c; pv2 = e;
        }
    }
    float info = info_level[b];
    float ang  = eps[b] * (1.0f - info) * SIGMA_MAXF;
    if (from_prior_p[0] != 0 && info == 0.0f) ang = uni[b];
    float ax = pv0-pu0, ay = pv1-pu1, az = pv2-pu2;
    float inv = 1.0f / (sqrtf(ax*ax + ay*ay + az*az) + 1e-12f);
    ax *= inv; ay *= inv; az *= inv;
    float c = cosf(ang), s = sinf(ang), t = 1.0f - c;
    float R00 = c + t*ax*ax,     R01 = -s*az + t*ax*ay, R02 =  s*ay + t*ax*az;
    float R10 =  s*az + t*ay*ax, R11 = c + t*ay*ay,     R12 = -s*ax + t*ay*az;
    float R20 = -s*ay + t*az*ax, R21 =  s*ax + t*az*ay, R22 = c + t*az*az;
    if (o == 0) {
        mg[0]=R00; mg[1]=R01; mg[2]=R02;
        mg[3]=R10; mg[4]=R11; mg[5]=R12;
        mg[6]=R20; mg[7]=R21; mg[8]=R22;
        mg[9]  = pv0 - (R00*pv0 + R01*pv1 + R02*pv2);
        mg[10] = pv1 - (R10*pv0 + R11*pv1 + R12*pv2);
        mg[11] = pv2 - (R20*pv0 + R21*pv1 + R22*pv2);
    } else {
        const float* mp = Mp + 12 * g;
        mg[0] = R00*mp[0] + R01*mp[3] + R02*mp[6];
        mg[1] = R00*mp[1] + R01*mp[4] + R02*mp[7];
        mg[2] = R00*mp[2] + R01*mp[5] + R02*mp[8];
        mg[3] = R10*mp[0] + R11*mp[3] + R12*mp[6];
        mg[4] = R10*mp[1] + R11*mp[4] + R12*mp[7];
        mg[5] = R10*mp[2] + R11*mp[5] + R12*mp[8];
        mg[6] = R20*mp[0] + R21*mp[3] + R22*mp[6];
        mg[7] = R20*mp[1] + R21*mp[4] + R22*mp[7];
        mg[8] = R20*mp[2] + R21*mp[5] + R22*mp[8];
        float d0 = mp[9]-pv0, d1 = mp[10]-pv1, d2 = mp[11]-pv2;
        mg[9]  = R00*d0 + R01*d1 + R02*d2 + pv0;
        mg[10] = R10*d0 + R11*d1 + R12*d2 + pv1;
        mg[11] = R20*d0 + R21*d1 + R22*d2 + pv2;
    }
}

// ---------------------------------------------------------------------------
// reduce_k: wave per domain; P = Mf * pos computed on the fly; 15 sums via
// shuffle; lane 0 stores to sums[d*15..]. All lanes useful.
// ---------------------------------------------------------------------------
__global__ __launch_bounds__(256) void reduce_k(const float* __restrict__ pos,
                                                const float* __restrict__ Mf,
                                                float* __restrict__ sums)
{
    int wave = threadIdx.x >> 6;
    int lane = threadIdx.x & 63;
    int d = blockIdx.x * 4 + wave;          // grid = 2500 -> d in [0,10000)
    float a[15];
    #pragma unroll
    for (int k = 0; k < 15; k++) a[k] = 0.f;
    for (int i = lane; i < N_PER_DOM; i += 64) {
        int n = d * N_PER_DOM + i;
        float q0 = pos[3*n+0], q1 = pos[3*n+1], q2 = pos[3*n+2];
        float p0 = q0, p1 = q1, p2 = q2;
        if (n < N_TWIST) {
            const float* m = Mf + 12 * (n / K_TWIST);
            p0 = m[0]*q0 + m[1]*q1 + m[2]*q2 + m[9];
            p1 = m[3]*q0 + m[4]*q1 + m[5]*q2 + m[10];
            p2 = m[6]*q0 + m[7]*q1 + m[8]*q2 + m[11];
        }
        a[0]+=p0;    a[1]+=p1;    a[2]+=p2;
        a[3]+=q0;    a[4]+=q1;    a[5]+=q2;
        a[6]+=p0*q0; a[7]+=p0*q1; a[8]+=p0*q2;
        a[9]+=p1*q0; a[10]+=p1*q1;a[11]+=p1*q2;
        a[12]+=p2*q0;a[13]+=p2*q1;a[14]+=p2*q2;
    }
    #pragma unroll
    for (int off = 32; off > 0; off >>= 1)
        #pragma unroll
        for (int k = 0; k < 15; k++) a[k] += __shfl_down(a[k], off);
    if (lane == 0) {
        float* sd = sums + (size_t)d * 15;
        #pragma unroll
        for (int k = 0; k < 15; k++) sd[k] = a[k];
    }
}

// ---------------------------------------------------------------------------
// 3x3 SVD-based Kabsch from 15 sums (double Jacobi on H^T H) — numerics
// identical to the R1/R3/R4-verified version.
// ---------------------------------------------------------------------------
__device__ inline void cross3d(const double a[3], const double b[3], double r[3])
{
    r[0] = a[1]*b[2] - a[2]*b[1];
    r[1] = a[2]*b[0] - a[0]*b[2];
    r[2] = a[0]*b[1] - a[1]*b[0];
}

__device__ void kabsch_from_sums(const float* s, float* __restrict__ rt)
{
    const double inv_n = 1.0 / (double)N_PER_DOM;
    double sP[3] = { s[0], s[1], s[2] };
    double sQ[3] = { s[3], s[4], s[5] };
    double H[3][3];
    #pragma unroll
    for (int i = 0; i < 3; i++)
        #pragma unroll
        for (int j = 0; j < 3; j++)
            H[i][j] = (double)s[6 + 3*i + j] - sP[i]*sQ[j]*inv_n;
    double A[3][3];
    #pragma unroll
    for (int i = 0; i < 3; i++)
        #pragma unroll
        for (int j = 0; j < 3; j++)
            A[i][j] = H[0][i]*H[0][j] + H[1][i]*H[1][j] + H[2][i]*H[2][j];
    double V[3][3] = {{1,0,0},{0,1,0},{0,0,1}};
    for (int sweep = 0; sweep < 30; sweep++) {
        double off = A[0][1]*A[0][1] + A[0][2]*A[0][2] + A[1][2]*A[1][2];
        double n2  = A[0][0]*A[0][0] + A[1][1]*A[1][1] + A[2][2]*A[2][2];
        if (off <= 1e-28 * n2) break;
        for (int pp = 0; pp < 3; pp++) {
            int p = (pp == 2) ? 1 : 0;
            int q = (pp == 0) ? 1 : 2;
            double apq = A[p][q];
            if (apq == 0.0) continue;
            double tau = (A[q][q] - A[p][p]) / (2.0 * apq);
            double tj  = (tau >= 0.0 ? 1.0 : -1.0) / (fabs(tau) + sqrt(1.0 + tau*tau));
            double cj  = 1.0 / sqrt(1.0 + tj*tj);
            double sj  = tj * cj;
            int r = 3 - p - q;
            double app = A[p][p], aqq = A[q][q];
            A[p][p] = app - tj*apq;
            A[q][q] = aqq + tj*apq;
            A[p][q] = 0.0; A[q][p] = 0.0;
            double arp = A[r][p], arq = A[r][q];
            A[r][p] = cj*arp - sj*arq; A[p][r] = A[r][p];
            A[r][q] = sj*arp + cj*arq; A[q][r] = A[r][q];
            #pragma unroll
            for (int k = 0; k < 3; k++) {
                double vp = V[k][p], vq = V[k][q];
                V[k][p] = cj*vp - sj*vq;
                V[k][q] = sj*vp + cj*vq;
            }
        }
    }
    double wv[3] = { A[0][0], A[1][1], A[2][2] };
    int i0 = 0, i1 = 1, i2 = 2;
    if (wv[i0] < wv[i1]) { int t = i0; i0 = i1; i1 = t; }
    if (wv[i0] < wv[i2]) { int t = i0; i0 = i2; i2 = t; }
    if (wv[i1] < wv[i2]) { int t = i1; i1 = i2; i2 = t; }
    double v0[3] = { V[0][i0], V[1][i0], V[2][i0] };
    double v1[3] = { V[0][i1], V[1][i1], V[2][i1] };
    double v2[3] = { V[0][i2], V[1][i2], V[2][i2] };
    double s0 = sqrt(fmax(wv[i0], 0.0));
    double Rg[3][3];
    if (s0 < 1e-200) {
        Rg[0][0]=1; Rg[0][1]=0; Rg[0][2]=0;
        Rg[1][0]=0; Rg[1][1]=1; Rg[1][2]=0;
        Rg[2][0]=0; Rg[2][1]=0; Rg[2][2]=1;
    } else {
        double u0[3], u1[3], u2[3];
        #pragma unroll
        for (int i = 0; i < 3; i++)
            u0[i] = H[i][0]*v0[0] + H[i][1]*v0[1] + H[i][2]*v0[2];
        double n0 = sqrt(u0[0]*u0[0] + u0[1]*u0[1] + u0[2]*u0[2]);
        if (n0 > 0.0) { u0[0]/=n0; u0[1]/=n0; u0[2]/=n0; }
        else { u0[0]=1; u0[1]=0; u0[2]=0; }
        #pragma unroll
        for (int i = 0; i < 3; i++)
            u1[i] = H[i][0]*v1[0] + H[i][1]*v1[1] + H[i][2]*v1[2];
        double dp = u0[0]*u1[0] + u0[1]*u1[1] + u0[2]*u1[2];
        u1[0] -= dp*u0[0]; u1[1] -= dp*u0[1]; u1[2] -= dp*u0[2];
        double n1 = sqrt(u1[0]*u1[0] + u1[1]*u1[1] + u1[2]*u1[2]);
        if (n1 > 1e-12 * n0) { u1[0]/=n1; u1[1]/=n1; u1[2]/=n1; }
        else {
            double tv[3] = { (fabs(u0[0]) < 0.9) ? 1.0 : 0.0,
                             (fabs(u0[0]) < 0.9) ? 0.0 : 1.0, 0.0 };
            cross3d(u0, tv, u1);
            double nn = sqrt(u1[0]*u1[0] + u1[1]*u1[1] + u1[2]*u1[2]);
            u1[0]/=nn; u1[1]/=nn; u1[2]/=nn;
        }
        cross3d(u0, u1, u2);                    // det(U) = +1
        double c12[3]; cross3d(v1, v2, c12);
        double detV = v0[0]*c12[0] + v0[1]*c12[1] + v0[2]*c12[2];
        double dsg = (detV >= 0.0) ? 1.0 : -1.0;
        #pragma unroll
        for (int r = 0; r < 3; r++)
            #pragma unroll
            for (int c = 0; c < 3; c++)
                Rg[r][c] = v0[r]*u0[c] + v1[r]*u1[c] + dsg*v2[r]*u2[c];
    }
    double cP[3] = { sP[0]*inv_n, sP[1]*inv_n, sP[2]*inv_n };
    double cQ[3] = { sQ[0]*inv_n, sQ[1]*inv_n, sQ[2]*inv_n };
    #pragma unroll
    for (int i = 0; i < 3; i++) {
        rt[3*i+0] = (float)Rg[i][0];
        rt[3*i+1] = (float)Rg[i][1];
        rt[3*i+2] = (float)Rg[i][2];
        rt[9+i] = (float)(cQ[i] - (Rg[i][0]*cP[0] + Rg[i][1]*cP[1] + Rg[i][2]*cP[2]));
    }
}

// ---------------------------------------------------------------------------
// svd_k: ONE THREAD per domain (all 64 lanes useful; 157 waves fully
// parallel across 256 CUs -> wall time ~ one SVD chain latency).
// ---------------------------------------------------------------------------
__global__ __launch_bounds__(128) void svd_k(const float* __restrict__ sums,
                                             float* __restrict__ rt)
{
    int d = blockIdx.x * 128 + threadIdx.x;
    if (d >= N_DOMAIN) return;
    kabsch_from_sums(sums + (size_t)d * 15, rt + (size_t)d * 12);
}

// ---------------------------------------------------------------------------
// apply_low_k: out[n] = Rg[d] * (Mf[g] * pos[n]) + t[d] for n < N_TWIST.
// Reads Mf (out-high scratch) — must precede apply_high_k.
// ---------------------------------------------------------------------------
__global__ void apply_low_k(const float* __restrict__ pos,
                            const float* __restrict__ Mf,
                            const float* __restrict__ rt,
                            float* __restrict__ out)
{
    int n = blockIdx.x * 256 + threadIdx.x;
    if (n >= N_TWIST) return;
    const float* m = Mf + 12 * (n / K_TWIST);
    const float* w = rt + 12 * (n / N_PER_DOM);
    float q0 = pos[3*n+0], q1 = pos[3*n+1], q2 = pos[3*n+2];
    float p0 = m[0]*q0 + m[1]*q1 + m[2]*q2 + m[9];
    float p1 = m[3]*q0 + m[4]*q1 + m[5]*q2 + m[10];
    float p2 = m[6]*q0 + m[7]*q1 + m[8]*q2 + m[11];
    out[3*n+0] = w[0]*p0 + w[1]*p1 + w[2]*p2 + w[9];
    out[3*n+1] = w[3]*p0 + w[4]*p1 + w[5]*p2 + w[10];
    out[3*n+2] = w[6]*p0 + w[7]*p1 + w[8]*p2 + w[11];
}

// ---------------------------------------------------------------------------
// apply_high_k: out[n] = Rg[d] * pos[n] + t[d] for n >= N_TWIST. Overwrites
// the out-high scratch (M0/M1/sums) — all consumed by now. rt lives in ws.
// ---------------------------------------------------------------------------
__global__ void apply_high_k(const float* __restrict__ pos,
                             const float* __restrict__ rt,
                             float* __restrict__ out)
{
    int i = blockIdx.x * 256 + threadIdx.x;
    int n = N_TWIST + i;
    if (n >= N_NODE) return;
    const float* w = rt + 12 * (n / N_PER_DOM);
    float q0 = pos[3*n+0], q1 = pos[3*n+1], q2 = pos[3*n+2];
    out[3*n+0] = w[0]*q0 + w[1]*q1 + w[2]*q2 + w[9];
    out[3*n+1] = w[3]*q0 + w[4]*q1 + w[5]*q2 + w[10];
    out[3*n+2] = w[6]*q0 + w[7]*q1 + w[8]*q2 + w[11];
}

// ---------------------------------------------------------------------------
extern "C" void kernel_launch(void* const* d_in, const int* in_sizes, int n_in,
                              void* d_out, int out_size, void* d_ws, size_t ws_size,
                              hipStream_t stream)
{
    const float* pos        = (const float*)d_in[0];
    const float* info_level = (const float*)d_in[1];
    const int*   anno       = (const int*)  d_in[2];
    const float* eps        = (const float*)d_in[6];
    const float* uni        = (const float*)d_in[7];
    const int*   from_prior = (const int*)  d_in[8];
    float* out = (float*)d_out;
    float* rt  = (float*)d_ws;                        // 480,000 B (proven safe)

    // scratch in out-high (floats [1.5M, 3M))
    float* M0   = out + (size_t)3 * N_TWIST;          // 150,000 floats
    float* M1   = M0 + 12 * N_GROUP;                  // 150,000 floats
    float* sums = M1 + 12 * N_GROUP;                  // 150,000 floats

    // Phase T: 8 tiny compose dispatches (ping-pong M0/M1; o=7 lands in M1).
    for (int o = 0; o < MAX_ORDER; o++) {
        const float* Mp = (o & 1) ? M0 : M1;
        float*       Mc = (o & 1) ? M1 : M0;
        compose_k<<<(N_GROUP + 255)/256, 256, 0, stream>>>(
            pos, info_level, anno, eps, uni, from_prior, Mp, Mc, o);
    }
    float* Mf = M1;

    // Phase R/S: reduce (wave/domain) then thread-per-domain SVD.
    reduce_k<<<N_DOMAIN / 4, 256, 0, stream>>>(pos, Mf, sums);
    svd_k<<<(N_DOMAIN + 127)/128, 128, 0, stream>>>(sums, rt);

    // Phase A: low nodes (reads Mf) then high nodes (overwrites scratch).
    apply_low_k<<<(N_TWIST + 255)/256, 256, 0, stream>>>(pos, Mf, rt, out);
    apply_high_k<<<(N_NODE - N_TWIST + 255)/256, 256, 0, stream>>>(pos, rt, out);
}